// Round 1
// baseline (453.576 us; speedup 1.0000x reference)
//
#include <hip/hip_runtime.h>
#include <math.h>

#define BATCH 64
#define CDIM 256
#define NDIM 784          // 28*28
#define TRIU (CDIM*(CDIM+1)/2)  // 32896
#define TILE 64
#define BK 16

// ---------------------------------------------------------------------------
// Row means: m[b,c] = mean over n of X[b,c,:]  (X is [B, C, N] row-major,
// which is exactly the raw input buffer reinterpreted).
// One wave per row.
__global__ __launch_bounds__(256)
void means_k(const float* __restrict__ X, float* __restrict__ means) {
    int row  = blockIdx.x * 4 + (threadIdx.x >> 6);   // 0..B*C-1
    int lane = threadIdx.x & 63;
    const float* p = X + (size_t)row * NDIM;
    float s = 0.f;
    for (int k = lane; k < NDIM; k += 64) s += p[k];
    for (int off = 32; off; off >>= 1) s += __shfl_down(s, off, 64);
    if (lane == 0) means[row] = s * (1.0f / NDIM);
}

// ---------------------------------------------------------------------------
// Gram: G[b] = X[b] * X[b]^T   (256x256, K=784). 64x64 tile, 4x4/thread.
__global__ __launch_bounds__(256)
void gram_k(const float* __restrict__ X, float* __restrict__ G) {
    __shared__ float As[BK][TILE];
    __shared__ float Bs[BK][TILE];
    const float* Xb = X + (size_t)blockIdx.y * CDIM * NDIM;
    float* Gb = G + (size_t)blockIdx.y * CDIM * CDIM;
    const int tile = blockIdx.x;
    const int rowBase = (tile >> 2) * TILE;
    const int colBase = (tile & 3) * TILE;
    const int tid = threadIdx.x;
    const int tx = tid & 15, ty = tid >> 4;
    const int lr = tid >> 2;            // 0..63 row within tile
    const int lk = (tid & 3) * 4;       // 0,4,8,12 k-seg
    float acc[4][4] = {};
    for (int k0 = 0; k0 < NDIM; k0 += BK) {
        float4 va = *(const float4*)(Xb + (size_t)(rowBase + lr) * NDIM + k0 + lk);
        float4 vb = *(const float4*)(Xb + (size_t)(colBase + lr) * NDIM + k0 + lk);
        __syncthreads();
        As[lk+0][lr] = va.x; As[lk+1][lr] = va.y; As[lk+2][lr] = va.z; As[lk+3][lr] = va.w;
        Bs[lk+0][lr] = vb.x; Bs[lk+1][lr] = vb.y; Bs[lk+2][lr] = vb.z; Bs[lk+3][lr] = vb.w;
        __syncthreads();
        #pragma unroll
        for (int kk = 0; kk < BK; ++kk) {
            float4 a4 = *(const float4*)&As[kk][ty * 4];
            float4 b4 = *(const float4*)&Bs[kk][tx * 4];
            float ae[4] = {a4.x, a4.y, a4.z, a4.w};
            float be[4] = {b4.x, b4.y, b4.z, b4.w};
            #pragma unroll
            for (int i = 0; i < 4; ++i)
                #pragma unroll
                for (int j = 0; j < 4; ++j)
                    acc[i][j] = fmaf(ae[i], be[j], acc[i][j]);
        }
    }
    const int orow = rowBase + ty * 4, ocol = colBase + tx * 4;
    #pragma unroll
    for (int i = 0; i < 4; ++i) {
        float4 r = make_float4(acc[i][0], acc[i][1], acc[i][2], acc[i][3]);
        *(float4*)(Gb + (size_t)(orow + i) * CDIM + ocol) = r;
    }
}

// ---------------------------------------------------------------------------
// Batched 256x256x256 GEMM.  MODE 0: Out = A*B.  MODE 1: Out = 1.5*Min - 0.5*(A*B)
template<int MODE>
__global__ __launch_bounds__(256)
void gemm_nn(const float* __restrict__ A, const float* __restrict__ Bm,
             const float* __restrict__ Min, float* __restrict__ Out) {
    __shared__ float As[BK][TILE];
    __shared__ float Bs[BK][TILE];
    const size_t moff = (size_t)blockIdx.y * CDIM * CDIM;
    A += moff; Bm += moff; Out += moff;
    if (MODE) Min += moff;
    const int tile = blockIdx.x;
    const int rowBase = (tile >> 2) * TILE;
    const int colBase = (tile & 3) * TILE;
    const int tid = threadIdx.x;
    const int tx = tid & 15, ty = tid >> 4;
    const int lr = tid >> 2;            // A-load: row 0..63
    const int lk = (tid & 3) * 4;       // A-load: k-seg
    const int bk = tid >> 4;            // B-load: k row 0..15
    const int bj = (tid & 15) * 4;      // B-load: col seg
    float acc[4][4] = {};
    for (int k0 = 0; k0 < CDIM; k0 += BK) {
        float4 va = *(const float4*)(A + (size_t)(rowBase + lr) * CDIM + k0 + lk);
        float4 vb = *(const float4*)(Bm + (size_t)(k0 + bk) * CDIM + colBase + bj);
        __syncthreads();
        As[lk+0][lr] = va.x; As[lk+1][lr] = va.y; As[lk+2][lr] = va.z; As[lk+3][lr] = va.w;
        *(float4*)&Bs[bk][bj] = vb;
        __syncthreads();
        #pragma unroll
        for (int kk = 0; kk < BK; ++kk) {
            float4 a4 = *(const float4*)&As[kk][ty * 4];
            float4 b4 = *(const float4*)&Bs[kk][tx * 4];
            float ae[4] = {a4.x, a4.y, a4.z, a4.w};
            float be[4] = {b4.x, b4.y, b4.z, b4.w};
            #pragma unroll
            for (int i = 0; i < 4; ++i)
                #pragma unroll
                for (int j = 0; j < 4; ++j)
                    acc[i][j] = fmaf(ae[i], be[j], acc[i][j]);
        }
    }
    const int orow = rowBase + ty * 4, ocol = colBase + tx * 4;
    #pragma unroll
    for (int i = 0; i < 4; ++i) {
        float4 r;
        float* o = Out + (size_t)(orow + i) * CDIM + ocol;
        if (MODE) {
            const float* mi = Min + (size_t)(orow + i) * CDIM + ocol;
            r.x = fmaf(1.5f, mi[0], -0.5f * acc[i][0]);
            r.y = fmaf(1.5f, mi[1], -0.5f * acc[i][1]);
            r.z = fmaf(1.5f, mi[2], -0.5f * acc[i][2]);
            r.w = fmaf(1.5f, mi[3], -0.5f * acc[i][3]);
        } else {
            r = make_float4(acc[i][0], acc[i][1], acc[i][2], acc[i][3]);
        }
        *(float4*)o = r;
    }
}

// ---------------------------------------------------------------------------
// trace[b] = sum_c (G[c][c]/n - m_c^2); store 1/trace and sqrt(trace).
__global__ __launch_bounds__(64)
void trace_k(const float* __restrict__ G, const float* __restrict__ means,
             float* __restrict__ itrace, float* __restrict__ strace) {
    int b = blockIdx.x, lane = threadIdx.x;
    float s = 0.f;
    #pragma unroll
    for (int i = 0; i < 4; ++i) {
        int c = lane + i * 64;
        float g = G[(size_t)b * CDIM * CDIM + (size_t)c * (CDIM + 1)];
        float m = means[b * CDIM + c];
        s += g * (1.0f / NDIM) - m * m;
    }
    for (int off = 32; off; off >>= 1) s += __shfl_down(s, off, 64);
    if (lane == 0) { itrace[b] = 1.0f / s; strace[b] = sqrtf(s); }
}

// ---------------------------------------------------------------------------
// A = (G/n - m_i m_j) / trace   -> Y buffer.  grid (C, B), 64 threads.
__global__ __launch_bounds__(64)
void init_k(const float* __restrict__ G, const float* __restrict__ means,
            const float* __restrict__ itrace, float* __restrict__ Y) {
    int b = blockIdx.y, i = blockIdx.x, j0 = threadIdx.x * 4;
    size_t base = (size_t)b * CDIM * CDIM + (size_t)i * CDIM;
    float mi = means[b * CDIM + i];
    float itr = itrace[b];
    float4 g = *(const float4*)(G + base + j0);
    const float* mj = means + b * CDIM + j0;
    float4 r;
    r.x = (g.x * (1.0f / NDIM) - mi * mj[0]) * itr;
    r.y = (g.y * (1.0f / NDIM) - mi * mj[1]) * itr;
    r.z = (g.z * (1.0f / NDIM) - mi * mj[2]) * itr;
    r.w = (g.w * (1.0f / NDIM) - mi * mj[3]) * itr;
    *(float4*)(Y + base + j0) = r;
}

// ---------------------------------------------------------------------------
// Z1 = 1.5*I - 0.5*Y1
__global__ __launch_bounds__(64)
void zinit_k(const float* __restrict__ Y1, float* __restrict__ Z) {
    int b = blockIdx.y, i = blockIdx.x, j0 = threadIdx.x * 4;
    size_t base = (size_t)b * CDIM * CDIM + (size_t)i * CDIM;
    float4 y = *(const float4*)(Y1 + base + j0);
    float r[4] = {-0.5f * y.x, -0.5f * y.y, -0.5f * y.z, -0.5f * y.w};
    if (i >= j0 && i < j0 + 4) r[i - j0] += 1.5f;
    float4 v = make_float4(r[0], r[1], r[2], r[3]);
    *(float4*)(Z + base + j0) = v;
}

// ---------------------------------------------------------------------------
// out[b, triu(r,c)] = sqrt(trace[b]) * Y[b,r,c]
__global__ __launch_bounds__(64)
void triu_k(const float* __restrict__ Y, const float* __restrict__ strace,
            float* __restrict__ out) {
    int b = blockIdx.y, r = blockIdx.x, lane = threadIdx.x;
    int len = CDIM - r;
    size_t ooff = (size_t)b * TRIU + (size_t)(r * CDIM - (r * (r - 1)) / 2);
    const float* yp = Y + (size_t)b * CDIM * CDIM + (size_t)r * CDIM + r;
    float s = strace[b];
    for (int t = lane; t < len; t += 64) out[ooff + t] = s * yp[t];
}

// ---------------------------------------------------------------------------
extern "C" void kernel_launch(void* const* d_in, const int* in_sizes, int n_in,
                              void* d_out, int out_size, void* d_ws, size_t ws_size,
                              hipStream_t stream) {
    const float* x = (const float*)d_in[0];
    float* out = (float*)d_out;
    float* ws  = (float*)d_ws;
    const size_t BCC = (size_t)BATCH * CDIM * CDIM;   // 4,194,304 floats
    float* buf0 = ws;                 // T / G
    float* buf1 = ws + BCC;           // Y_a
    float* buf2 = ws + 2 * BCC;       // Y_b / Z_b
    float* buf3 = ws + 3 * BCC;       // Z_a / final Y
    float* means  = ws + 4 * BCC;     // B*C
    float* itrace = means + BATCH * CDIM;  // B
    float* strace = itrace + BATCH;        // B
    // total: 4*BCC + 16384 + 128 floats ~= 67.2 MB

    means_k<<<BATCH * CDIM / 4, 256, 0, stream>>>(x, means);
    gram_k <<<dim3(16, BATCH), 256, 0, stream>>>(x, buf0);          // G = X X^T
    trace_k<<<BATCH, 64, 0, stream>>>(buf0, means, itrace, strace);
    init_k <<<dim3(CDIM, BATCH), 64, 0, stream>>>(buf0, means, itrace, buf1);  // A

    // iter 1 (Z=I):  Y1 = 1.5A - 0.5 A*A ;  Z1 = 1.5I - 0.5 Y1
    gemm_nn<1><<<dim3(16, BATCH), 256, 0, stream>>>(buf1, buf1, buf1, buf2);   // Y1 -> buf2
    zinit_k   <<<dim3(CDIM, BATCH), 64, 0, stream>>>(buf2, buf3);              // Z1 -> buf3
    // iter 2:
    gemm_nn<0><<<dim3(16, BATCH), 256, 0, stream>>>(buf3, buf2, nullptr, buf0); // T  = Z1*Y1
    gemm_nn<1><<<dim3(16, BATCH), 256, 0, stream>>>(buf2, buf0, buf2, buf1);    // Y2 = 1.5Y1-0.5 Y1*T
    gemm_nn<0><<<dim3(16, BATCH), 256, 0, stream>>>(buf3, buf1, nullptr, buf0); // T2 = Z1*Y2
    gemm_nn<1><<<dim3(16, BATCH), 256, 0, stream>>>(buf0, buf3, buf3, buf2);    // Z2 = 1.5Z1-0.5 T2*Z1
    // iter 3 (Z-update dead):
    gemm_nn<0><<<dim3(16, BATCH), 256, 0, stream>>>(buf2, buf1, nullptr, buf0); // T3 = Z2*Y2
    gemm_nn<1><<<dim3(16, BATCH), 256, 0, stream>>>(buf1, buf0, buf1, buf3);    // Y3 = 1.5Y2-0.5 Y2*T3

    triu_k<<<dim3(CDIM, BATCH), 64, 0, stream>>>(buf3, strace, out);
}

// Round 2
// 376.555 us; speedup vs baseline: 1.2045x; 1.2045x over previous
//
#include <hip/hip_runtime.h>
#include <math.h>

#define BATCH 64
#define CD 256
#define NX 784
#define TRIU_N (CD*(CD+1)/2)

typedef unsigned short ushort_t;
typedef unsigned int uint_t;
typedef __attribute__((ext_vector_type(8))) short short8;
typedef __attribute__((ext_vector_type(16))) float floatx16;

// bf16 round-to-nearest-even helpers (no NaN/inf in this workload)
__device__ __forceinline__ ushort_t f2bf(float x) {
    uint_t u = __float_as_uint(x);
    u += 0x7fffu + ((u >> 16) & 1u);
    return (ushort_t)(u >> 16);
}
__device__ __forceinline__ float bf2f(ushort_t h) {
    return __uint_as_float(((uint_t)h) << 16);
}
__device__ __forceinline__ void split2(float x, ushort_t& h, ushort_t& l) {
    h = f2bf(x);
    l = f2bf(x - bf2f(h));
}

// ---------------------------------------------------------------------------
// Row means over n=784. One wave per row.
__global__ __launch_bounds__(256)
void means_k(const float* __restrict__ X, float* __restrict__ means) {
    int row  = blockIdx.x * 4 + (threadIdx.x >> 6);
    int lane = threadIdx.x & 63;
    const float* p = X + (size_t)row * NX;
    float s = 0.f;
    for (int k = lane; k < NX; k += 64) s += p[k];
    for (int off = 32; off; off >>= 1) s += __shfl_down(s, off, 64);
    if (lane == 0) means[row] = s * (1.0f / NX);
}

// ---------------------------------------------------------------------------
// MFMA core helper: one BK=32 stage of 32x32x16 bf16 MFMAs (split-2, 3 products)
// LDS layout per array (4096 elems): [k16][khalf][row128][8] bf16
__device__ __forceinline__ void mfma_stage(const ushort_t* lds, int wr, int wc,
                                           int khalf, int lrow, floatx16 acc[2][2]) {
    #pragma unroll
    for (int ks = 0; ks < 2; ++ks) {
        short8 aH[2], aL[2], bH[2], bL[2];
        #pragma unroll
        for (int rt = 0; rt < 2; ++rt) {
            int eo = ks*2048 + khalf*1024 + (wr*64 + rt*32 + lrow)*8;
            aH[rt] = *(const short8*)(lds + eo);
            aL[rt] = *(const short8*)(lds + 4096 + eo);
        }
        #pragma unroll
        for (int ct = 0; ct < 2; ++ct) {
            int eo = ks*2048 + khalf*1024 + (wc*64 + ct*32 + lrow)*8;
            bH[ct] = *(const short8*)(lds + 8192 + eo);
            bL[ct] = *(const short8*)(lds + 12288 + eo);
        }
        #pragma unroll
        for (int rt = 0; rt < 2; ++rt)
        #pragma unroll
        for (int ct = 0; ct < 2; ++ct) {
            acc[rt][ct] = __builtin_amdgcn_mfma_f32_32x32x16_bf16(aH[rt], bH[ct], acc[rt][ct], 0, 0, 0);
            acc[rt][ct] = __builtin_amdgcn_mfma_f32_32x32x16_bf16(aH[rt], bL[ct], acc[rt][ct], 0, 0, 0);
            acc[rt][ct] = __builtin_amdgcn_mfma_f32_32x32x16_bf16(aL[rt], bH[ct], acc[rt][ct], 0, 0, 0);
        }
    }
}

// ---------------------------------------------------------------------------
// Gram: Sigma = X*X^T/n - m m^T, staged from fp32 X with in-register split.
// Output in split bf16 (hi, lo). Tile 128x128, K padded 784->800 via zero chunks.
__global__ __launch_bounds__(256, 1)
void gram_mfma(const float* __restrict__ X, const float* __restrict__ means,
               ushort_t* __restrict__ Ghi, ushort_t* __restrict__ Glo) {
    __shared__ ushort_t lds[16384];   // 32 KB: Ahi|Alo|Bhi|Blo, 4096 elems each
    const int bb = blockIdx.y;
    const int tileId = blockIdx.x;
    const int rowBase = (tileId >> 1) * 128;
    const int colBase = (tileId & 1) * 128;
    const int tid = threadIdx.x;
    const int lane = tid & 63, wv = tid >> 6;
    const int wr = wv >> 1, wc = wv & 1;
    const int khalf = lane >> 5, lrow = lane & 31;

    floatx16 acc[2][2];
    #pragma unroll
    for (int a = 0; a < 2; ++a)
        #pragma unroll
        for (int b = 0; b < 2; ++b)
            #pragma unroll
            for (int i = 0; i < 16; ++i) acc[a][b][i] = 0.f;

    const float* Xb = X + (size_t)bb * CD * NX;

    for (int k0 = 0; k0 < 800; k0 += 32) {   // 25 stages
        __syncthreads();
        #pragma unroll
        for (int q = 0; q < 4; ++q) {
            const int side = q >> 1;                 // 0 = A rows, 1 = B rows
            const int c = (q & 1) * 256 + tid;       // 0..511
            const int row = c >> 2;
            const int kq = c & 3;
            const int gk = k0 + kq * 8;
            float v[8];
            if (gk < NX) {
                const float* s = Xb + (size_t)((side ? colBase : rowBase) + row) * NX + gk;
                float4 a = *(const float4*)s;
                float4 b = *(const float4*)(s + 4);
                v[0]=a.x; v[1]=a.y; v[2]=a.z; v[3]=a.w;
                v[4]=b.x; v[5]=b.y; v[6]=b.z; v[7]=b.w;
            } else {
                #pragma unroll
                for (int i = 0; i < 8; ++i) v[i] = 0.f;
            }
            uint_t hp[4], lp[4];
            #pragma unroll
            for (int i = 0; i < 4; ++i) {
                ushort_t h0, l0, h1, l1;
                split2(v[2*i], h0, l0);
                split2(v[2*i+1], h1, l1);
                hp[i] = (uint_t)h0 | ((uint_t)h1 << 16);
                lp[i] = (uint_t)l0 | ((uint_t)l1 << 16);
            }
            const int eo = (kq >> 1) * 2048 + (kq & 1) * 1024 + row * 8;
            *(uint4*)(lds + side * 8192 + eo)        = make_uint4(hp[0], hp[1], hp[2], hp[3]);
            *(uint4*)(lds + side * 8192 + 4096 + eo) = make_uint4(lp[0], lp[1], lp[2], lp[3]);
        }
        __syncthreads();
        mfma_stage(lds, wr, wc, khalf, lrow, acc);
    }

    // epilogue: Sigma = acc/n - m_r m_c, split write
    const float* mb = means + bb * CD;
    const size_t gb = (size_t)bb * CD * CD;
    #pragma unroll
    for (int rt = 0; rt < 2; ++rt)
    #pragma unroll
    for (int ct = 0; ct < 2; ++ct)
        #pragma unroll
        for (int i = 0; i < 16; ++i) {
            int rl = (i & 3) + ((i >> 2) << 3) + ((lane >> 5) << 2);
            int r = rowBase + wr * 64 + rt * 32 + rl;
            int c = colBase + wc * 64 + ct * 32 + (lane & 31);
            float sig = acc[rt][ct][i] * (1.0f / NX) - mb[r] * mb[c];
            ushort_t h, l;
            split2(sig, h, l);
            Ghi[gb + (size_t)r * CD + c] = h;
            Glo[gb + (size_t)r * CD + c] = l;
        }
}

// ---------------------------------------------------------------------------
// trace from split Sigma diagonal; store 1/trace and sqrt(trace)
__global__ __launch_bounds__(64)
void trace_k(const ushort_t* __restrict__ Ghi, const ushort_t* __restrict__ Glo,
             float* __restrict__ itr, float* __restrict__ str) {
    int b = blockIdx.x, lane = threadIdx.x;
    float s = 0.f;
    #pragma unroll
    for (int i = 0; i < 4; ++i) {
        int c = lane + i * 64;
        size_t d = (size_t)b * CD * CD + (size_t)c * (CD + 1);
        s += bf2f(Ghi[d]) + bf2f(Glo[d]);
    }
    for (int off = 32; off; off >>= 1) s += __shfl_down(s, off, 64);
    if (lane == 0) { itr[b] = 1.0f / s; str[b] = sqrtf(s); }
}

// ---------------------------------------------------------------------------
// A = Sigma / trace, in-place resplit
__global__ __launch_bounds__(256)
void scale_k(ushort_t* __restrict__ Shi, ushort_t* __restrict__ Slo,
             const float* __restrict__ itr) {
    size_t i4 = ((size_t)blockIdx.x * 256 + threadIdx.x) * 4;
    int b = (int)(i4 >> 16);
    float t = itr[b];
    ushort4 h = *(ushort4*)(Shi + i4);
    ushort4 l = *(ushort4*)(Slo + i4);
    float a0 = (bf2f(h.x) + bf2f(l.x)) * t;
    float a1 = (bf2f(h.y) + bf2f(l.y)) * t;
    float a2 = (bf2f(h.z) + bf2f(l.z)) * t;
    float a3 = (bf2f(h.w) + bf2f(l.w)) * t;
    split2(a0, h.x, l.x); split2(a1, h.y, l.y);
    split2(a2, h.z, l.z); split2(a3, h.w, l.w);
    *(ushort4*)(Shi + i4) = h;
    *(ushort4*)(Slo + i4) = l;
}

// ---------------------------------------------------------------------------
// NS GEMM: C = Aop * Bop^T (all matrices symmetric => row-major k-contig both sides)
// MODE 1 PLAIN: O1 = acc (split)
// MODE 2 Y:     O1 = 1.5*Min - 0.5*acc (split)
// MODE 3 YZ:    O1 = y = 1.5*Min - 0.5*acc; O2 = 1.5*I - 0.5*y (both split)
// MODE 4 TRIU:  out[triu] = strace * (1.5*Min - 0.5*acc)
template<int MODE>
__global__ __launch_bounds__(256, 1)
void ns_mfma(const ushort_t* __restrict__ Ahi, const ushort_t* __restrict__ Alo,
             const ushort_t* __restrict__ Bhi, const ushort_t* __restrict__ Blo,
             const ushort_t* __restrict__ Mhi, const ushort_t* __restrict__ Mlo,
             const float* __restrict__ strace,
             ushort_t* __restrict__ O1hi, ushort_t* __restrict__ O1lo,
             ushort_t* __restrict__ O2hi, ushort_t* __restrict__ O2lo,
             float* __restrict__ outT) {
    const int tileId = blockIdx.x;
    const int rowBase = (tileId >> 1) * 128;
    const int colBase = (tileId & 1) * 128;
    if (MODE == 4 && rowBase > colBase) return;   // tile fully below diagonal

    __shared__ ushort_t lds[16384];
    const int bb = blockIdx.y;
    const size_t mb = (size_t)bb * CD * CD;
    const int tid = threadIdx.x;
    const int lane = tid & 63, wv = tid >> 6;
    const int wr = wv >> 1, wc = wv & 1;
    const int khalf = lane >> 5, lrow = lane & 31;

    floatx16 acc[2][2];
    #pragma unroll
    for (int a = 0; a < 2; ++a)
        #pragma unroll
        for (int b = 0; b < 2; ++b)
            #pragma unroll
            for (int i = 0; i < 16; ++i) acc[a][b][i] = 0.f;

    for (int k0 = 0; k0 < CD; k0 += 32) {   // 8 stages
        __syncthreads();
        #pragma unroll
        for (int q = 0; q < 8; ++q) {
            const int arr = q >> 1;                  // 0:Ahi 1:Alo 2:Bhi 3:Blo
            const int c = (q & 1) * 256 + tid;       // 0..511
            const int row = c >> 2;
            const int kq = c & 3;
            const ushort_t* sp = (arr == 0) ? (Ahi + mb) : (arr == 1) ? (Alo + mb)
                               : (arr == 2) ? (Bhi + mb) : (Blo + mb);
            const int br = (arr < 2) ? rowBase : colBase;
            uint4 v = *(const uint4*)(sp + (size_t)(br + row) * CD + k0 + kq * 8);
            const int eo = (kq >> 1) * 2048 + (kq & 1) * 1024 + row * 8;
            *(uint4*)(lds + arr * 4096 + eo) = v;
        }
        __syncthreads();
        mfma_stage(lds, wr, wc, khalf, lrow, acc);
    }

    const float st = (MODE == 4) ? strace[bb] : 0.f;
    #pragma unroll
    for (int rt = 0; rt < 2; ++rt)
    #pragma unroll
    for (int ct = 0; ct < 2; ++ct)
        #pragma unroll
        for (int i = 0; i < 16; ++i) {
            int rl = (i & 3) + ((i >> 2) << 3) + ((lane >> 5) << 2);
            int r = rowBase + wr * 64 + rt * 32 + rl;
            int c = colBase + wc * 64 + ct * 32 + (lane & 31);
            float v = acc[rt][ct][i];
            size_t idx = mb + (size_t)r * CD + c;
            if (MODE == 1) {
                ushort_t h, l;
                split2(v, h, l);
                O1hi[idx] = h; O1lo[idx] = l;
            } else {
                float m = bf2f(Mhi[idx]) + bf2f(Mlo[idx]);
                float y = fmaf(1.5f, m, -0.5f * v);
                if (MODE == 2) {
                    ushort_t h, l;
                    split2(y, h, l);
                    O1hi[idx] = h; O1lo[idx] = l;
                } else if (MODE == 3) {
                    ushort_t h, l;
                    split2(y, h, l);
                    O1hi[idx] = h; O1lo[idx] = l;
                    float z = ((r == c) ? 1.5f : 0.f) - 0.5f * y;
                    split2(z, h, l);
                    O2hi[idx] = h; O2lo[idx] = l;
                } else {  // TRIU
                    if (c >= r) {
                        size_t oi = (size_t)bb * TRIU_N
                                  + (size_t)((r * CD - (r * (r - 1)) / 2) + (c - r));
                        outT[oi] = st * y;
                    }
                }
            }
        }
}

// ---------------------------------------------------------------------------
extern "C" void kernel_launch(void* const* d_in, const int* in_sizes, int n_in,
                              void* d_out, int out_size, void* d_ws, size_t ws_size,
                              hipStream_t stream) {
    const float* x = (const float*)d_in[0];
    float* out = (float*)d_out;
    char* ws = (char*)d_ws;
    const size_t HSZ = (size_t)BATCH * CD * CD * 2;   // 8,388,608 B per half-matrix
    ushort_t* S0h = (ushort_t*)(ws + 0 * HSZ);
    ushort_t* S0l = (ushort_t*)(ws + 1 * HSZ);
    ushort_t* S1h = (ushort_t*)(ws + 2 * HSZ);
    ushort_t* S1l = (ushort_t*)(ws + 3 * HSZ);
    ushort_t* S2h = (ushort_t*)(ws + 4 * HSZ);
    ushort_t* S2l = (ushort_t*)(ws + 5 * HSZ);
    ushort_t* S3h = (ushort_t*)(ws + 6 * HSZ);
    ushort_t* S3l = (ushort_t*)(ws + 7 * HSZ);
    float* means = (float*)(ws + 8 * HSZ);          // 64*256 floats
    float* itr = means + BATCH * CD;                // 64
    float* str = itr + BATCH;                       // 64
    // total ws: 64 MB + 66 KB  (same footprint class as round 1)

    means_k<<<BATCH * CD / 4, 256, 0, stream>>>(x, means);
    gram_mfma<<<dim3(4, BATCH), 256, 0, stream>>>(x, means, S0h, S0l);   // Sigma -> S0
    trace_k<<<BATCH, 64, 0, stream>>>(S0h, S0l, itr, str);
    scale_k<<<4096, 256, 0, stream>>>(S0h, S0l, itr);                    // A -> S0

    // iter1: Y1 = 1.5A - 0.5 A*A -> S1 ; Z1 = 1.5I - 0.5 Y1 -> S2
    ns_mfma<3><<<dim3(4, BATCH), 256, 0, stream>>>(S0h, S0l, S0h, S0l, S0h, S0l,
                                                   nullptr, S1h, S1l, S2h, S2l, nullptr);
    // T1 = Z1*Y1 -> S3
    ns_mfma<1><<<dim3(4, BATCH), 256, 0, stream>>>(S2h, S2l, S1h, S1l, nullptr, nullptr,
                                                   nullptr, S3h, S3l, nullptr, nullptr, nullptr);
    // Y2 = 1.5 Y1 - 0.5 Y1*T1 -> S0   (A dead)
    ns_mfma<2><<<dim3(4, BATCH), 256, 0, stream>>>(S1h, S1l, S3h, S3l, S1h, S1l,
                                                   nullptr, S0h, S0l, nullptr, nullptr, nullptr);
    // T2 = Z1*Y2 -> S3  (T1 dead)
    ns_mfma<1><<<dim3(4, BATCH), 256, 0, stream>>>(S2h, S2l, S0h, S0l, nullptr, nullptr,
                                                   nullptr, S3h, S3l, nullptr, nullptr, nullptr);
    // Z2 = 1.5 Z1 - 0.5 T2*Z1 -> S1   (Y1 dead)
    ns_mfma<2><<<dim3(4, BATCH), 256, 0, stream>>>(S3h, S3l, S2h, S2l, S2h, S2l,
                                                   nullptr, S1h, S1l, nullptr, nullptr, nullptr);
    // T3 = Z2*Y2 -> S3  (T2 dead)
    ns_mfma<1><<<dim3(4, BATCH), 256, 0, stream>>>(S1h, S1l, S0h, S0l, nullptr, nullptr,
                                                   nullptr, S3h, S3l, nullptr, nullptr, nullptr);
    // out = strace * (1.5 Y2 - 0.5 Y2*T3), triu-packed
    ns_mfma<4><<<dim3(4, BATCH), 256, 0, stream>>>(S0h, S0l, S3h, S3l, S0h, S0l,
                                                   str, nullptr, nullptr, nullptr, nullptr, out);
}

// Round 3
// 262.429 us; speedup vs baseline: 1.7284x; 1.4349x over previous
//
#include <hip/hip_runtime.h>
#include <math.h>

#define BATCH 64
#define CD 256
#define NX 784
#define TRIU_N 32896
#define MSZ 65536           // elems per swizzled 256x256 matrix
#define REG_STRIDE 1032     // 128 rows * 8 elems + 8 pad (bank-conflict break)
#define ARR_STRIDE 4128     // 4 regions
#define BUF_STRIDE 16512    // 4 arrays (Ahi,Alo,Bhi,Blo)

typedef unsigned short ushort_t;
typedef unsigned int uint_t;
typedef __attribute__((ext_vector_type(8))) short short8;
typedef __attribute__((ext_vector_type(8))) unsigned short ushort8;
typedef __attribute__((ext_vector_type(16))) float floatx16;

__device__ __forceinline__ ushort_t f2bf(float x) {
    uint_t u = __float_as_uint(x);
    u += 0x7fffu + ((u >> 16) & 1u);
    return (ushort_t)(u >> 16);
}
__device__ __forceinline__ float bf2f(ushort_t h) {
    return __uint_as_float(((uint_t)h) << 16);
}
__device__ __forceinline__ void split2(float x, ushort_t& h, ushort_t& l) {
    h = f2bf(x);
    l = f2bf(x - bf2f(h));
}

// swizzled offset of element (r,c) within one 256x256 matrix:
// [p=r>>7][s=c>>5][ks=(c>>4)&1][kh=(c>>3)&1][r&127][c&7]  (dense, no pad in global)
__device__ __forceinline__ int swoff(int r, int c) {
    int p = r >> 7, s = (c >> 5) & 7, ks = (c >> 4) & 1, kh = (c >> 3) & 1;
    return ((((p * 8 + s) * 2 + ks) * 2 + kh) * 128 + (r & 127)) * 8 + (c & 7);
}

// ---------------------------------------------------------------------------
__global__ __launch_bounds__(256)
void means_k(const float* __restrict__ X, float* __restrict__ means) {
    int row  = blockIdx.x * 4 + (threadIdx.x >> 6);
    int lane = threadIdx.x & 63;
    const float* p = X + (size_t)row * NX;
    float s = 0.f;
    for (int k = lane; k < NX; k += 64) s += p[k];
    for (int off = 32; off; off >>= 1) s += __shfl_down(s, off, 64);
    if (lane == 0) means[row] = s * (1.0f / NX);
}

// ---------------------------------------------------------------------------
// One BK=32 stage: wave computes 2 quadrants (wr, wcp*2+{0,1}) of 32x32.
// 12 ds_read_b128 + 12 MFMA per wave per stage.
__device__ __forceinline__ void mfma_stage8(const ushort_t* us, int bufbase,
                                            int wr, int wcp, int khalf, int lrow,
                                            floatx16* acc) {
    #pragma unroll
    for (int ks = 0; ks < 2; ++ks) {
        const int rid = ks * 2 + khalf;
        const ushort_t* rb = us + bufbase + rid * REG_STRIDE + lrow * 8;
        short8 aH = *(const short8*)(rb + wr * 256);
        short8 aL = *(const short8*)(rb + ARR_STRIDE + wr * 256);
        #pragma unroll
        for (int cq = 0; cq < 2; ++cq) {
            const int col = wcp * 2 + cq;
            short8 bH = *(const short8*)(rb + 2 * ARR_STRIDE + col * 256);
            short8 bL = *(const short8*)(rb + 3 * ARR_STRIDE + col * 256);
            acc[cq] = __builtin_amdgcn_mfma_f32_32x32x16_bf16(aH, bH, acc[cq], 0, 0, 0);
            acc[cq] = __builtin_amdgcn_mfma_f32_32x32x16_bf16(aH, bL, acc[cq], 0, 0, 0);
            acc[cq] = __builtin_amdgcn_mfma_f32_32x32x16_bf16(aL, bH, acc[cq], 0, 0, 0);
        }
    }
}

// ---------------------------------------------------------------------------
// Gram: Sigma = X X^T / n - m m^T. In-register fp32->bf16 split-2 staging,
// double-buffered LDS, swizzled split output. Tile 128x128, K 784 (25 stages).
__global__ __launch_bounds__(512, 1)
void gram_mfma(const float* __restrict__ X, const float* __restrict__ means,
               ushort_t* __restrict__ Gh, ushort_t* __restrict__ Gl) {
    __shared__ __align__(16) float fsmem[16512];   // 66 KB: 2 staging bufs OR epilogue tile
    ushort_t* us = (ushort_t*)fsmem;
    const int bb = blockIdx.y, tile = blockIdx.x;
    const int rowBase = (tile >> 1) * 128, colBase = (tile & 1) * 128;
    const int tid = threadIdx.x, lane = tid & 63, wv = tid >> 6;
    const int wr = wv >> 1, wcp = wv & 1;
    const int khalf = lane >> 5, lrow = lane & 31;
    const float* Xb = X + (size_t)bb * CD * NX;

    floatx16 acc[2];
    #pragma unroll
    for (int cq = 0; cq < 2; ++cq)
        #pragma unroll
        for (int i = 0; i < 16; ++i) acc[cq][i] = 0.f;

    int side[2], srow[2], skq[2];
    #pragma unroll
    for (int q = 0; q < 2; ++q) {
        int gid = q * 512 + tid;
        side[q] = gid >> 9;
        srow[q] = (gid >> 2) & 127;
        skq[q]  = gid & 3;
    }

    float4 cur[2][2];
    // prologue: load + write stage 0
    #pragma unroll
    for (int q = 0; q < 2; ++q) {
        int gk = skq[q] * 8;
        const float* p = Xb + (size_t)((side[q] ? colBase : rowBase) + srow[q]) * NX + gk;
        cur[q][0] = *(const float4*)p;
        cur[q][1] = *(const float4*)(p + 4);
    }
    #pragma unroll
    for (int q = 0; q < 2; ++q) {
        float f[8] = {cur[q][0].x, cur[q][0].y, cur[q][0].z, cur[q][0].w,
                      cur[q][1].x, cur[q][1].y, cur[q][1].z, cur[q][1].w};
        uint_t hp[4], lp[4];
        #pragma unroll
        for (int i = 0; i < 4; ++i) {
            ushort_t h0, l0, h1, l1;
            split2(f[2*i], h0, l0); split2(f[2*i+1], h1, l1);
            hp[i] = (uint_t)h0 | ((uint_t)h1 << 16);
            lp[i] = (uint_t)l0 | ((uint_t)l1 << 16);
        }
        int base = (side[q] * 2) * ARR_STRIDE + skq[q] * REG_STRIDE + srow[q] * 8;
        *(uint4*)(us + base)              = make_uint4(hp[0], hp[1], hp[2], hp[3]);
        *(uint4*)(us + base + ARR_STRIDE) = make_uint4(lp[0], lp[1], lp[2], lp[3]);
    }

    for (int s = 0; s < 25; ++s) {
        __syncthreads();
        bool more = (s + 1 < 25);
        if (more) {
            #pragma unroll
            for (int q = 0; q < 2; ++q) {
                int gk = (s + 1) * 32 + skq[q] * 8;
                if (gk < NX) {
                    const float* p = Xb + (size_t)((side[q] ? colBase : rowBase) + srow[q]) * NX + gk;
                    cur[q][0] = *(const float4*)p;
                    cur[q][1] = *(const float4*)(p + 4);
                } else {
                    cur[q][0] = make_float4(0.f, 0.f, 0.f, 0.f);
                    cur[q][1] = make_float4(0.f, 0.f, 0.f, 0.f);
                }
            }
        }
        mfma_stage8(us, (s & 1) * BUF_STRIDE, wr, wcp, khalf, lrow, acc);
        if (more) {
            int buf = (s + 1) & 1;
            #pragma unroll
            for (int q = 0; q < 2; ++q) {
                float f[8] = {cur[q][0].x, cur[q][0].y, cur[q][0].z, cur[q][0].w,
                              cur[q][1].x, cur[q][1].y, cur[q][1].z, cur[q][1].w};
                uint_t hp[4], lp[4];
                #pragma unroll
                for (int i = 0; i < 4; ++i) {
                    ushort_t h0, l0, h1, l1;
                    split2(f[2*i], h0, l0); split2(f[2*i+1], h1, l1);
                    hp[i] = (uint_t)h0 | ((uint_t)h1 << 16);
                    lp[i] = (uint_t)l0 | ((uint_t)l1 << 16);
                }
                int base = buf * BUF_STRIDE + (side[q] * 2) * ARR_STRIDE
                         + skq[q] * REG_STRIDE + srow[q] * 8;
                *(uint4*)(us + base)              = make_uint4(hp[0], hp[1], hp[2], hp[3]);
                *(uint4*)(us + base + ARR_STRIDE) = make_uint4(lp[0], lp[1], lp[2], lp[3]);
            }
        }
    }

    // epilogue via LDS bounce (stride 129 -> conflict-free)
    __syncthreads();
    #pragma unroll
    for (int cq = 0; cq < 2; ++cq)
        #pragma unroll
        for (int i = 0; i < 16; ++i) {
            int rl = (i & 3) + ((i >> 2) << 3) + (khalf << 2);
            fsmem[(wr * 32 + rl) * 129 + (wcp * 2 + cq) * 32 + lrow] = acc[cq][i];
        }
    __syncthreads();
    const int rloc = tid & 127;
    const int r = rowBase + rloc;
    const float mr = means[bb * CD + r];
    #pragma unroll
    for (int gi = 0; gi < 4; ++gi) {
        int g = (tid >> 7) + gi * 4;
        int c0 = colBase + g * 8;
        int so = swoff(r, c0);
        ushort8 hh, ll;
        #pragma unroll
        for (int j = 0; j < 8; ++j) {
            float v = fsmem[rloc * 129 + g * 8 + j] * (1.0f / NX) - mr * means[bb * CD + c0 + j];
            ushort_t h, l; split2(v, h, l);
            hh[j] = h; ll[j] = l;
        }
        *(ushort8*)(Gh + (size_t)bb * MSZ + so) = hh;
        *(ushort8*)(Gl + (size_t)bb * MSZ + so) = ll;
    }
}

// ---------------------------------------------------------------------------
__global__ __launch_bounds__(64)
void trace_k(const ushort_t* __restrict__ Gh, const ushort_t* __restrict__ Gl,
             float* __restrict__ itr, float* __restrict__ str_) {
    int b = blockIdx.x, lane = threadIdx.x;
    float s = 0.f;
    #pragma unroll
    for (int i = 0; i < 4; ++i) {
        int c = lane + i * 64;
        size_t d = (size_t)b * MSZ + swoff(c, c);
        s += bf2f(Gh[d]) + bf2f(Gl[d]);
    }
    for (int off = 32; off; off >>= 1) s += __shfl_down(s, off, 64);
    if (lane == 0) { itr[b] = 1.0f / s; str_[b] = sqrtf(s); }
}

// ---------------------------------------------------------------------------
__device__ __forceinline__ void ns_prefetch(const ushort_t* const* arrp, ushort_t* us,
                                            int wv, int lane, int s, int buf) {
    #pragma unroll
    for (int j = 0; j < 4; ++j) {
        int ck = wv * 4 + j;
        int arr = ck >> 3, rid = (ck >> 1) & 3, half = ck & 1;
        const ushort_t* g = arrp[arr] + s * 4096 + rid * 1024 + half * 512 + lane * 8;
        ushort_t* l = us + buf * BUF_STRIDE + arr * ARR_STRIDE + rid * REG_STRIDE + half * 512;
        __builtin_amdgcn_global_load_lds(
            (const __attribute__((address_space(1))) unsigned int*)g,
            (__attribute__((address_space(3))) unsigned int*)l, 16, 0, 0);
    }
}

// NS GEMM on swizzled split-bf16 operands (all symmetric => NT, k-contig both).
// MODE 0: O1 = acc
// MODE 1: O1 = 1.5*M - 0.5*acc
// MODE 2: y = 1.5*it*M - 0.5*it^2*acc; O1=y; O2 = 1.5*I - 0.5*y   (iter1 from Sigma)
// MODE 3: out_triu = st * (1.5*M - 0.5*acc)
template<int MODE>
__global__ __launch_bounds__(512, 1)
void ns_mfma(const ushort_t* __restrict__ Ah, const ushort_t* __restrict__ Al,
             const ushort_t* __restrict__ Bh, const ushort_t* __restrict__ Bl,
             const ushort_t* __restrict__ Mh, const ushort_t* __restrict__ Ml,
             const float* __restrict__ itr, const float* __restrict__ str_,
             ushort_t* __restrict__ O1h, ushort_t* __restrict__ O1l,
             ushort_t* __restrict__ O2h, ushort_t* __restrict__ O2l,
             float* __restrict__ outT) {
    const int tile = blockIdx.x;
    const int rowBase = (tile >> 1) * 128, colBase = (tile & 1) * 128;
    if (MODE == 3 && rowBase > colBase) return;
    __shared__ __align__(16) float fsmem[16512];
    ushort_t* us = (ushort_t*)fsmem;
    const int bb = blockIdx.y;
    const size_t mb = (size_t)bb * MSZ;
    const int tid = threadIdx.x, lane = tid & 63, wv = tid >> 6;
    const int wr = wv >> 1, wcp = wv & 1;
    const int khalf = lane >> 5, lrow = lane & 31;
    const ushort_t* arrp[4] = {
        Ah + mb + (size_t)(rowBase >> 7) * 32768,
        Al + mb + (size_t)(rowBase >> 7) * 32768,
        Bh + mb + (size_t)(colBase >> 7) * 32768,
        Bl + mb + (size_t)(colBase >> 7) * 32768 };

    floatx16 acc[2];
    #pragma unroll
    for (int cq = 0; cq < 2; ++cq)
        #pragma unroll
        for (int i = 0; i < 16; ++i) acc[cq][i] = 0.f;

    ns_prefetch(arrp, us, wv, lane, 0, 0);
    #pragma unroll
    for (int s = 0; s < 8; ++s) {
        __syncthreads();
        if (s < 7) ns_prefetch(arrp, us, wv, lane, s + 1, (s + 1) & 1);
        mfma_stage8(us, (s & 1) * BUF_STRIDE, wr, wcp, khalf, lrow, acc);
    }

    __syncthreads();
    #pragma unroll
    for (int cq = 0; cq < 2; ++cq)
        #pragma unroll
        for (int i = 0; i < 16; ++i) {
            int rl = (i & 3) + ((i >> 2) << 3) + (khalf << 2);
            fsmem[(wr * 32 + rl) * 129 + (wcp * 2 + cq) * 32 + lrow] = acc[cq][i];
        }
    __syncthreads();
    const int rloc = tid & 127;
    const int r = rowBase + rloc;
    float it = 0.f, st = 0.f;
    if (MODE == 2) it = itr[bb];
    if (MODE == 3) st = str_[bb];
    #pragma unroll
    for (int gi = 0; gi < 4; ++gi) {
        int g = (tid >> 7) + gi * 4;
        int c0 = colBase + g * 8;
        int so = swoff(r, c0);
        float v[8];
        #pragma unroll
        for (int j = 0; j < 8; ++j) v[j] = fsmem[rloc * 129 + g * 8 + j];
        if (MODE == 0) {
            ushort8 hh, ll;
            #pragma unroll
            for (int j = 0; j < 8; ++j) {
                ushort_t h, l; split2(v[j], h, l);
                hh[j] = h; ll[j] = l;
            }
            *(ushort8*)(O1h + mb + so) = hh;
            *(ushort8*)(O1l + mb + so) = ll;
        } else {
            ushort8 mh = *(const ushort8*)(Mh + mb + so);
            ushort8 mlv = *(const ushort8*)(Ml + mb + so);
            if (MODE == 1) {
                ushort8 hh, ll;
                #pragma unroll
                for (int j = 0; j < 8; ++j) {
                    float m = bf2f(mh[j]) + bf2f(mlv[j]);
                    float y = fmaf(1.5f, m, -0.5f * v[j]);
                    ushort_t h, l; split2(y, h, l);
                    hh[j] = h; ll[j] = l;
                }
                *(ushort8*)(O1h + mb + so) = hh;
                *(ushort8*)(O1l + mb + so) = ll;
            } else if (MODE == 2) {
                ushort8 yh, yl, zh, zl;
                #pragma unroll
                for (int j = 0; j < 8; ++j) {
                    float m = bf2f(mh[j]) + bf2f(mlv[j]);
                    float y = 1.5f * it * m - 0.5f * it * it * v[j];
                    float z = ((r == c0 + j) ? 1.5f : 0.f) - 0.5f * y;
                    ushort_t h, l;
                    split2(y, h, l); yh[j] = h; yl[j] = l;
                    split2(z, h, l); zh[j] = h; zl[j] = l;
                }
                *(ushort8*)(O1h + mb + so) = yh;
                *(ushort8*)(O1l + mb + so) = yl;
                *(ushort8*)(O2h + mb + so) = zh;
                *(ushort8*)(O2l + mb + so) = zl;
            } else {
                int tb = r * CD - (r * (r - 1)) / 2 - r;
                #pragma unroll
                for (int j = 0; j < 8; ++j) {
                    float m = bf2f(mh[j]) + bf2f(mlv[j]);
                    float y = fmaf(1.5f, m, -0.5f * v[j]);
                    int c = c0 + j;
                    if (c >= r) outT[(size_t)bb * TRIU_N + tb + c] = st * y;
                }
            }
        }
    }
}

// ---------------------------------------------------------------------------
extern "C" void kernel_launch(void* const* d_in, const int* in_sizes, int n_in,
                              void* d_out, int out_size, void* d_ws, size_t ws_size,
                              hipStream_t stream) {
    const float* x = (const float*)d_in[0];
    float* out = (float*)d_out;
    char* ws = (char*)d_ws;
    const size_t HS = (size_t)BATCH * MSZ * 2;   // bytes per matrix array (8 MB)
    ushort_t* S0h = (ushort_t*)(ws + 0 * HS);
    ushort_t* S0l = (ushort_t*)(ws + 1 * HS);
    ushort_t* S1h = (ushort_t*)(ws + 2 * HS);
    ushort_t* S1l = (ushort_t*)(ws + 3 * HS);
    ushort_t* S2h = (ushort_t*)(ws + 4 * HS);
    ushort_t* S2l = (ushort_t*)(ws + 5 * HS);
    ushort_t* S3h = (ushort_t*)(ws + 6 * HS);
    ushort_t* S3l = (ushort_t*)(ws + 7 * HS);
    float* means = (float*)(ws + 8 * HS);
    float* itr = means + BATCH * CD;
    float* str_ = itr + BATCH;

    dim3 gG(4, BATCH);
    means_k<<<BATCH * CD / 4, 256, 0, stream>>>(x, means);
    gram_mfma<<<gG, 512, 0, stream>>>(x, means, S0h, S0l);              // Sigma -> S0
    trace_k<<<BATCH, 64, 0, stream>>>(S0h, S0l, itr, str_);
    // iter1 (scale folded): Y1 -> S1, Z1 -> S2
    ns_mfma<2><<<gG, 512, 0, stream>>>(S0h, S0l, S0h, S0l, S0h, S0l,
                                       itr, nullptr, S1h, S1l, S2h, S2l, nullptr);
    // T1 = Z1*Y1 -> S3
    ns_mfma<0><<<gG, 512, 0, stream>>>(S2h, S2l, S1h, S1l, nullptr, nullptr,
                                       nullptr, nullptr, S3h, S3l, nullptr, nullptr, nullptr);
    // Y2 = 1.5Y1 - 0.5 Y1*T1 -> S0
    ns_mfma<1><<<gG, 512, 0, stream>>>(S1h, S1l, S3h, S3l, S1h, S1l,
                                       nullptr, nullptr, S0h, S0l, nullptr, nullptr, nullptr);
    // T2 = Z1*Y2 -> S3
    ns_mfma<0><<<gG, 512, 0, stream>>>(S2h, S2l, S0h, S0l, nullptr, nullptr,
                                       nullptr, nullptr, S3h, S3l, nullptr, nullptr, nullptr);
    // Z2 = 1.5Z1 - 0.5 T2*Z1 -> S1  (M = B = Z1)
    ns_mfma<1><<<gG, 512, 0, stream>>>(S3h, S3l, S2h, S2l, S2h, S2l,
                                       nullptr, nullptr, S1h, S1l, nullptr, nullptr, nullptr);
    // T3 = Z2*Y2 -> S3
    ns_mfma<0><<<gG, 512, 0, stream>>>(S1h, S1l, S0h, S0l, nullptr, nullptr,
                                       nullptr, nullptr, S3h, S3l, nullptr, nullptr, nullptr);
    // out = st * (1.5 Y2 - 0.5 Y2*T3), triu-packed
    ns_mfma<3><<<gG, 512, 0, stream>>>(S0h, S0l, S3h, S3l, S0h, S0l,
                                       nullptr, str_, nullptr, nullptr, nullptr, nullptr, out);
}